// Round 5
// baseline (302.899 us; speedup 1.0000x reference)
//
#include <hip/hip_runtime.h>

// VQEmbedding: B=32,T=1024,D=256,K=1024. N=32768 rows.
// Exact score (proven r2-r4): s = fl32( fl32(csqr_k + xsqr_i) - 2*dot_ik ), argmin,
// first-index ties. bf16 MFMA gives approx dots (layout verified r4); two-pass margin:
// pass1 = packed-u32 per-row min (no atomics), pass2 = recompute + append codes within
// MARGIN, then exact fp32 rescore (r2-proven chain) + u64-key atomicMin (first-index).
// r4 lesson: keep VGPR <= ~128 (spill caused 26MB scratch writes + 200us stall) and
// >= 4 blocks/CU for latency hiding.

#define NROWS  32768
#define DDIM   256
#define KCODES 1024
#define MARGIN 1e-3f
#define CAP    512

typedef __attribute__((ext_vector_type(8))) short short8;
typedef __attribute__((ext_vector_type(4))) float f32x4;

__device__ __forceinline__ unsigned short f2bf(float f) {   // RNE f32->bf16
    unsigned u = __float_as_uint(f);
    return (unsigned short)((u + 0x7FFFu + ((u >> 16) & 1u)) >> 16);
}

// exact fp32 dot — BIT-IDENTICAL chain to r2/r3/r4 (proven): two halves of 128
// sequential FMAs, one final add. DO NOT reorder.
__device__ __forceinline__ float exact_dot(const float* __restrict__ xrow,
                                           const float* __restrict__ crow) {
    const float4* xp = (const float4*)xrow;
    const float4* cp = (const float4*)crow;
    float A = 0.f, B = 0.f;
    #pragma unroll 8
    for (int d4 = 0; d4 < 32; ++d4) {
        float4 xv = xp[d4], cv = cp[d4];
        A = __fmaf_rn(xv.x, cv.x, A);
        A = __fmaf_rn(xv.y, cv.y, A);
        A = __fmaf_rn(xv.z, cv.z, A);
        A = __fmaf_rn(xv.w, cv.w, A);
    }
    #pragma unroll 8
    for (int d4 = 32; d4 < 64; ++d4) {
        float4 xv = xp[d4], cv = cp[d4];
        B = __fmaf_rn(xv.x, cv.x, B);
        B = __fmaf_rn(xv.y, cv.y, B);
        B = __fmaf_rn(xv.z, cv.z, B);
        B = __fmaf_rn(xv.w, cv.w, B);
    }
    return __fadd_rn(A, B);
}

// --- csqr[k] = sum_d cb[k][d]^2 (proven r2-r4, unchanged) ---
__global__ __launch_bounds__(256) void vq_csqr(const float* __restrict__ cb,
                                               float* __restrict__ csqr) {
    int gid  = blockIdx.x * 256 + threadIdx.x;
    int w    = gid >> 6;
    int lane = threadIdx.x & 63;
    if (w >= KCODES) return;
    float4 v = reinterpret_cast<const float4*>(cb)[w * (DDIM / 4) + lane];
    float s = v.x * v.x + v.y * v.y + v.z * v.z + v.w * v.w;
    #pragma unroll
    for (int off = 32; off > 0; off >>= 1) s += __shfl_down(s, off, 64);
    if (lane == 0) csqr[w] = s;
}

// --- xsqr[r] (proven r3/r4, unchanged — numerics must stay bit-identical) ---
__global__ __launch_bounds__(256) void vq_xsqr(const float* __restrict__ x,
                                               float* __restrict__ xsqr) {
    int w = threadIdx.x >> 6, lane = threadIdx.x & 63;
    int row = blockIdx.x * 4 + w;
    float4 v = reinterpret_cast<const float4*>(x + (size_t)row * DDIM)[lane];
    float s = v.x * v.x + v.y * v.y + v.z * v.z + v.w * v.w;
    #pragma unroll
    for (int off = 32; off > 0; off >>= 1) s += __shfl_down(s, off, 64);
    if (lane == 0) xsqr[row] = s;
}

// --- cb -> bf16 B-fragments (layout VERIFIED by r4): frag(nt,ks): lane l elem i =
//     cb[nt*16 + (l&15)][ks*32 + (l>>4)*8 + i]; linear id = (nt*8+ks)*64 + l ---
__global__ __launch_bounds__(256) void vq_cbfrag(const float* __restrict__ cb,
                                                 short* __restrict__ cbh) {
    int id   = blockIdx.x * 256 + threadIdx.x;
    int lane = id & 63;
    int ks   = (id >> 6) & 7;
    int nt   = id >> 9;
    int code = nt * 16 + (lane & 15);
    int d0   = ks * 32 + (lane >> 4) * 8;
    const float4* p = (const float4*)(cb + (size_t)code * DDIM + d0);
    float4 a = p[0], b = p[1];
    short8 v;
    v[0] = (short)f2bf(a.x); v[1] = (short)f2bf(a.y);
    v[2] = (short)f2bf(a.z); v[3] = (short)f2bf(a.w);
    v[4] = (short)f2bf(b.x); v[5] = (short)f2bf(b.y);
    v[6] = (short)f2bf(b.z); v[7] = (short)f2bf(b.w);
    *(short8*)(cbh + (size_t)id * 8) = v;
}

// --- main: 32 rows/block, 256 thr = 4 waves = (tile 0/1) x (code-half 0/1) ---
__global__ __launch_bounds__(256, 3) void vq_main(const float* __restrict__ x,
                                                  const float* __restrict__ cb,
                                                  const short* __restrict__ cbh,
                                                  const float* __restrict__ csqr,
                                                  const float* __restrict__ xsqr,
                                                  float* __restrict__ out) {
    __shared__ float              csl[KCODES];
    __shared__ unsigned           kred[4][16];
    __shared__ float              thrsh[32];
    __shared__ unsigned long long keys[32];
    __shared__ unsigned           list[CAP];
    __shared__ int                fidx[32];
    __shared__ int                cnt, ovf;

    const int t    = threadIdx.x;
    const int lane = t & 63;
    const int w    = t >> 6;          // 0..3
    const int tile = w >> 1;          // row-tile
    const int q    = w & 1;           // code half
    const int r0   = blockIdx.x * 32;
    const int lr   = lane & 15;
    const int lg   = lane >> 4;

    ((float4*)csl)[t] = ((const float4*)csqr)[t];
    if (t < 32) keys[t] = ~0ULL;
    if (t == 0) { cnt = 0; ovf = 0; }

    // A-fragments (one 16-row tile per wave; pattern identical to r4)
    short8 afr[8];
    {
        int row = r0 + tile * 16 + lr;
        #pragma unroll
        for (int ks = 0; ks < 8; ++ks) {
            const float4* p = (const float4*)(x + (size_t)row * DDIM + ks * 32 + lg * 8);
            float4 a = p[0], b = p[1];
            short8 v;
            v[0] = (short)f2bf(a.x); v[1] = (short)f2bf(a.y);
            v[2] = (short)f2bf(a.z); v[3] = (short)f2bf(a.w);
            v[4] = (short)f2bf(b.x); v[5] = (short)f2bf(b.y);
            v[6] = (short)f2bf(b.z); v[7] = (short)f2bf(b.w);
            afr[ks] = v;
        }
    }
    __syncthreads();

    // ---- pass 1: per-row coarse min, branchless packed u32 (scorebits&~1023 | code) ----
    unsigned run[4] = {~0u, ~0u, ~0u, ~0u};
    for (int ch = 0; ch < 4; ++ch) {
        f32x4 af[8];
        #pragma unroll
        for (int n = 0; n < 8; ++n) af[n] = (f32x4){0.f, 0.f, 0.f, 0.f};
        #pragma unroll
        for (int ks = 0; ks < 8; ++ks) {
            short8 bv[8];
            #pragma unroll
            for (int n = 0; n < 8; ++n) {
                int nt = q * 32 + ch * 8 + n;
                bv[n] = *(const short8*)(cbh + (size_t)((nt * 8 + ks) * 64 + lane) * 8);
            }
            #pragma unroll
            for (int n = 0; n < 8; ++n)
                af[n] = __builtin_amdgcn_mfma_f32_16x16x32_bf16(afr[ks], bv[n], af[n], 0, 0, 0);
        }
        const int cbase = q * 512 + ch * 128 + lr;
        #pragma unroll
        for (int n = 0; n < 8; ++n) {
            float cs1 = __fadd_rn(csl[cbase + n * 16], 1.0f);   // +1: score>0, bit order = float order
            #pragma unroll
            for (int j = 0; j < 4; ++j) {
                float s = __fmaf_rn(-2.f, af[n][j], cs1);
                unsigned kp = (__float_as_uint(s) & 0xFFFFFC00u) | (unsigned)(cbase + n * 16);
                run[j] = run[j] < kp ? run[j] : kp;
            }
        }
    }
    #pragma unroll
    for (int j = 0; j < 4; ++j) {
        #pragma unroll
        for (int m = 1; m < 16; m <<= 1) {
            unsigned o = __shfl_xor(run[j], m, 64);
            run[j] = run[j] < o ? run[j] : o;
        }
    }
    if (lr == 0) {
        #pragma unroll
        for (int j = 0; j < 4; ++j) kred[w][lg * 4 + j] = run[j];
    }
    __syncthreads();
    if (t < 32) {
        int tl = t >> 4, rr = t & 15;
        unsigned a = kred[tl * 2][rr], b = kred[tl * 2 + 1][rr];
        unsigned m = a < b ? a : b;
        thrsh[t] = __uint_as_float(m & 0xFFFFFC00u) + MARGIN;   // coarse lower bound + margin
    }
    __syncthreads();

    // ---- pass 2: recompute (bit-identical), append candidates <= thr ----
    for (int ch = 0; ch < 4; ++ch) {
        f32x4 af[8];
        #pragma unroll
        for (int n = 0; n < 8; ++n) af[n] = (f32x4){0.f, 0.f, 0.f, 0.f};
        #pragma unroll
        for (int ks = 0; ks < 8; ++ks) {
            short8 bv[8];
            #pragma unroll
            for (int n = 0; n < 8; ++n) {
                int nt = q * 32 + ch * 8 + n;
                bv[n] = *(const short8*)(cbh + (size_t)((nt * 8 + ks) * 64 + lane) * 8);
            }
            #pragma unroll
            for (int n = 0; n < 8; ++n)
                af[n] = __builtin_amdgcn_mfma_f32_16x16x32_bf16(afr[ks], bv[n], af[n], 0, 0, 0);
        }
        const int cbase = q * 512 + ch * 128 + lr;
        #pragma unroll
        for (int n = 0; n < 8; ++n) {
            float cs1 = __fadd_rn(csl[cbase + n * 16], 1.0f);
            #pragma unroll
            for (int j = 0; j < 4; ++j) {
                float s   = __fmaf_rn(-2.f, af[n][j], cs1);
                int   row = tile * 16 + lg * 4 + j;
                if (s <= thrsh[row]) {
                    int pos = atomicAdd(&cnt, 1);
                    if (pos < CAP) list[pos] = ((unsigned)row << 10) | (unsigned)(cbase + n * 16);
                    else ovf = 1;
                }
            }
        }
    }
    __syncthreads();

    // ---- exact rescore (r2-proven chain + grid formula), u64 first-index argmin ----
    if (ovf || cnt > CAP) {
        for (int it = t; it < 32 * KCODES; it += 256) {        // safety net (never fires)
            int row = it >> 10, code = it & (KCODES - 1);
            float dot = exact_dot(x + (size_t)(r0 + row) * DDIM, cb + (size_t)code * DDIM);
            float s   = __fmaf_rn(-2.f, dot, __fadd_rn(csl[code], xsqr[r0 + row]));
            atomicMin(&keys[row], ((unsigned long long)__float_as_uint(s) << 32) | (unsigned)code);
        }
    } else {
        for (int i = t; i < cnt; i += 256) {
            unsigned e = list[i];
            int row = (int)(e >> 10), code = (int)(e & 0x3FFu);
            float dot = exact_dot(x + (size_t)(r0 + row) * DDIM, cb + (size_t)code * DDIM);
            float s   = __fmaf_rn(-2.f, dot, __fadd_rn(csl[code], xsqr[r0 + row]));
            atomicMin(&keys[row], ((unsigned long long)__float_as_uint(s) << 32) | (unsigned)code);
        }
    }
    __syncthreads();

    if (t < 32) {
        int code = (int)(unsigned)(keys[t] & 0xffffffffu);
        fidx[t] = code;
        out[(size_t)2 * NROWS * DDIM + (r0 + t)] = (float)code;
    }
    __syncthreads();

    const float4* cb4  = (const float4*)cb;
    float4*       out0 = (float4*)out;
    float4*       out1 = out0 + (size_t)NROWS * (DDIM / 4);
    #pragma unroll
    for (int i = 0; i < 8; ++i) {
        int it  = i * 256 + t;            // 32 rows x 64 float4
        int row = it >> 6, col = it & 63;
        float4 v = cb4[(size_t)fidx[row] * (DDIM / 4) + col];
        size_t o = (size_t)(r0 + row) * (DDIM / 4) + col;
        out0[o] = v;
        out1[o] = v;
    }
}

extern "C" void kernel_launch(void* const* d_in, const int* in_sizes, int n_in,
                              void* d_out, int out_size, void* d_ws, size_t ws_size,
                              hipStream_t stream) {
    const float* x   = (const float*)d_in[0];   // z_e_x   [32768,256]
    const float* cb  = (const float*)d_in[1];   // codebook [1024,256]
    float*       out = (float*)d_out;

    float* ws_csqr = (float*)d_ws;                // [1024]
    float* ws_xsqr = ws_csqr + KCODES;            // [32768]
    short* ws_cbh  = (short*)(ws_xsqr + NROWS);   // [1024*256] bf16 frags

    vq_cbfrag<<<128,       256, 0, stream>>>(cb, ws_cbh);
    vq_csqr  <<<256,       256, 0, stream>>>(cb, ws_csqr);
    vq_xsqr  <<<NROWS / 4, 256, 0, stream>>>(x, ws_xsqr);
    vq_main  <<<NROWS / 32, 256, 0, stream>>>(x, cb, ws_cbh, ws_csqr, ws_xsqr, out);
}

// Round 6
// 99.938 us; speedup vs baseline: 3.0309x; 3.0309x over previous
//
#include <hip/hip_runtime.h>

// VQEmbedding: B=32,T=1024,D=256,K=1024. N=32768 rows.
// Exact score (proven r2-r5): s = fl32( fl32(csqr_k + xsqr_i) - 2*dot_ik ), argmin,
// first-index ties via packed u64 keys. bf16 MFMA approx dots (fragment layout verified
// r4/r5); two-pass margin filter; exact fp32 rescore with the r2-proven chain reading
// x from LDS (bit-identical values).
// r5 lesson: keep the MFMA accumulator to ONE f32x4 so all 8 B-fragment loads batch
// (MLP=8); r4 lesson: stay under the VGPR cap; rescore must NOT re-read x from HBM.

#define NROWS  32768
#define DDIM   256
#define KCODES 1024
#define MARGIN 1.5e-3f
#define CAP    1024
#define RPB    64          // rows per block
#define XPITCH 260         // padded floats per LDS x row (260%4==0 for float4; 2-way banks)

typedef __attribute__((ext_vector_type(8))) short short8;
typedef __attribute__((ext_vector_type(4))) float f32x4;

__device__ __forceinline__ unsigned short f2bf(float f) {   // RNE f32->bf16
    unsigned u = __float_as_uint(f);
    return (unsigned short)((u + 0x7FFFu + ((u >> 16) & 1u)) >> 16);
}

// exact fp32 dot — BIT-IDENTICAL chain to r2-r5 (proven): two halves of 128 sequential
// FMAs, one final add. xrow may point to LDS (same values as global x -> same bits).
__device__ __forceinline__ float exact_dot(const float* __restrict__ xrow,
                                           const float* __restrict__ crow) {
    const float4* xp = (const float4*)xrow;
    const float4* cp = (const float4*)crow;
    float A = 0.f, B = 0.f;
    #pragma unroll 8
    for (int d4 = 0; d4 < 32; ++d4) {
        float4 xv = xp[d4], cv = cp[d4];
        A = __fmaf_rn(xv.x, cv.x, A);
        A = __fmaf_rn(xv.y, cv.y, A);
        A = __fmaf_rn(xv.z, cv.z, A);
        A = __fmaf_rn(xv.w, cv.w, A);
    }
    #pragma unroll 8
    for (int d4 = 32; d4 < 64; ++d4) {
        float4 xv = xp[d4], cv = cp[d4];
        B = __fmaf_rn(xv.x, cv.x, B);
        B = __fmaf_rn(xv.y, cv.y, B);
        B = __fmaf_rn(xv.z, cv.z, B);
        B = __fmaf_rn(xv.w, cv.w, B);
    }
    return __fadd_rn(A, B);
}

// --- csqr[k] (proven r2-r5, unchanged) ---
__global__ __launch_bounds__(256) void vq_csqr(const float* __restrict__ cb,
                                               float* __restrict__ csqr) {
    int gid  = blockIdx.x * 256 + threadIdx.x;
    int w    = gid >> 6;
    int lane = threadIdx.x & 63;
    if (w >= KCODES) return;
    float4 v = reinterpret_cast<const float4*>(cb)[w * (DDIM / 4) + lane];
    float s = v.x * v.x + v.y * v.y + v.z * v.z + v.w * v.w;
    #pragma unroll
    for (int off = 32; off > 0; off >>= 1) s += __shfl_down(s, off, 64);
    if (lane == 0) csqr[w] = s;
}

// --- xsqr[r] (proven r3-r5, unchanged) ---
__global__ __launch_bounds__(256) void vq_xsqr(const float* __restrict__ x,
                                               float* __restrict__ xsqr) {
    int w = threadIdx.x >> 6, lane = threadIdx.x & 63;
    int row = blockIdx.x * 4 + w;
    float4 v = reinterpret_cast<const float4*>(x + (size_t)row * DDIM)[lane];
    float s = v.x * v.x + v.y * v.y + v.z * v.z + v.w * v.w;
    #pragma unroll
    for (int off = 32; off > 0; off >>= 1) s += __shfl_down(s, off, 64);
    if (lane == 0) xsqr[row] = s;
}

// --- cb -> bf16 B-fragments (layout verified r4/r5): frag(nt,ks): lane l elem i =
//     cb[nt*16 + (l&15)][ks*32 + (l>>4)*8 + i]; linear id = (nt*8+ks)*64 + l ---
__global__ __launch_bounds__(256) void vq_cbfrag(const float* __restrict__ cb,
                                                 short* __restrict__ cbh) {
    int id   = blockIdx.x * 256 + threadIdx.x;
    int lane = id & 63;
    int ks   = (id >> 6) & 7;
    int nt   = id >> 9;
    int code = nt * 16 + (lane & 15);
    int d0   = ks * 32 + (lane >> 4) * 8;
    const float4* p = (const float4*)(cb + (size_t)code * DDIM + d0);
    float4 a = p[0], b = p[1];
    short8 v;
    v[0] = (short)f2bf(a.x); v[1] = (short)f2bf(a.y);
    v[2] = (short)f2bf(a.z); v[3] = (short)f2bf(a.w);
    v[4] = (short)f2bf(b.x); v[5] = (short)f2bf(b.y);
    v[6] = (short)f2bf(b.z); v[7] = (short)f2bf(b.w);
    *(short8*)(cbh + (size_t)id * 8) = v;
}

// one 16-row x 16-code x K=256 tile: 8 batched B-loads (MLP=8), 8 chained MFMAs.
// MFMA order fixed -> pass1/pass2 results bit-identical.
__device__ __forceinline__ f32x4 dot_tile(const short8 (&afr)[8],
                                          const short8* __restrict__ cbh8,
                                          int nt, int lane) {
    const short8* bp = cbh8 + (size_t)nt * 8 * 64 + lane;
    short8 bv[8];
    #pragma unroll
    for (int ks = 0; ks < 8; ++ks) bv[ks] = bp[(size_t)ks * 64];
    f32x4 af = (f32x4){0.f, 0.f, 0.f, 0.f};
    #pragma unroll
    for (int ks = 0; ks < 8; ++ks)
        af = __builtin_amdgcn_mfma_f32_16x16x32_bf16(afr[ks], bv[ks], af, 0, 0, 0);
    return af;
}

// --- main: 64 rows/block, 512 thr = 8 waves = 4 row-tiles x 2 code-halves ---
__global__ __launch_bounds__(512, 4) void vq_main(const float* __restrict__ x,
                                                  const float* __restrict__ cb,
                                                  const short* __restrict__ cbh,
                                                  const float* __restrict__ csqr,
                                                  const float* __restrict__ xsqr,
                                                  float* __restrict__ out) {
    __shared__ float              xl[RPB * XPITCH];   // 66560 B, padded rows
    __shared__ float              csl[KCODES];        // 4 KB
    __shared__ unsigned           kred[8][16];
    __shared__ float              thrsh[RPB];
    __shared__ unsigned long long keys[RPB];
    __shared__ unsigned           list[CAP];
    __shared__ int                fidx[RPB];
    __shared__ int                cnt, ovf;

    const int t    = threadIdx.x;
    const int lane = t & 63;
    const int w    = t >> 6;         // 0..7
    const int tile = w >> 1;         // 0..3 (16-row tile)
    const int q    = w & 1;          // code half
    const int r0   = blockIdx.x * RPB;
    const int lr   = lane & 15;
    const int lg   = lane >> 4;

    if (t < 256) ((float4*)csl)[t] = ((const float4*)csqr)[t];
    if (t < RPB) keys[t] = ~0ULL;
    if (t == 0) { cnt = 0; ovf = 0; }

    // stage x tile: i = row*64 + c4, lane-consecutive c4 -> coalesced 1KB/wave-instr;
    // LDS write bank = (row + l) % 32, 2-way = free.
    {
        const float4* xg = (const float4*)(x + (size_t)r0 * DDIM);
        #pragma unroll
        for (int kk = 0; kk < 8; ++kk) {
            int i   = kk * 512 + t;
            int row = i >> 6, c4 = i & 63;
            float4 v = xg[i];
            *(float4*)&xl[row * XPITCH + c4 * 4] = v;
        }
    }
    __syncthreads();

    // A-fragments from LDS (same element mapping as r4/r5, verified)
    short8 afr[8];
    {
        const float* xr = &xl[(tile * 16 + lr) * XPITCH];
        #pragma unroll
        for (int ks = 0; ks < 8; ++ks) {
            float4 a = *(const float4*)&xr[ks * 32 + lg * 8];
            float4 b = *(const float4*)&xr[ks * 32 + lg * 8 + 4];
            short8 v;
            v[0] = (short)f2bf(a.x); v[1] = (short)f2bf(a.y);
            v[2] = (short)f2bf(a.z); v[3] = (short)f2bf(a.w);
            v[4] = (short)f2bf(b.x); v[5] = (short)f2bf(b.y);
            v[6] = (short)f2bf(b.z); v[7] = (short)f2bf(b.w);
            afr[ks] = v;
        }
    }

    const short8* cbh8 = (const short8*)cbh;

    // ---- pass 1: coarse per-row min, packed u32 (score_bits&~1023 | code) ----
    unsigned run[4] = {~0u, ~0u, ~0u, ~0u};
    for (int nn = 0; nn < 32; ++nn) {
        int nt = q * 32 + nn;
        f32x4 af = dot_tile(afr, cbh8, nt, lane);
        int   code = nt * 16 + lr;
        float cs1  = __fadd_rn(csl[code], 1.0f);   // +1: score>0 -> bit order = float order
        #pragma unroll
        for (int j = 0; j < 4; ++j) {
            float s = __fmaf_rn(-2.f, af[j], cs1);
            unsigned kp = (__float_as_uint(s) & 0xFFFFFC00u) | (unsigned)code;
            run[j] = run[j] < kp ? run[j] : kp;
        }
    }
    #pragma unroll
    for (int j = 0; j < 4; ++j) {
        unsigned v = run[j];
        #pragma unroll
        for (int m = 1; m < 16; m <<= 1) {
            unsigned o = __shfl_xor(v, m, 64);
            v = o < v ? o : v;
        }
        run[j] = v;
    }
    if (lr == 0) {
        #pragma unroll
        for (int j = 0; j < 4; ++j) kred[w][lg * 4 + j] = run[j];
    }
    __syncthreads();
    if (t < RPB) {
        int tl = t >> 4, rr = t & 15;
        unsigned a = kred[tl * 2][rr], b = kred[tl * 2 + 1][rr];
        unsigned m = a < b ? a : b;
        thrsh[t] = __uint_as_float(m & 0xFFFFFC00u) + MARGIN;   // trunc(min)+M, sound per bound
    }
    __syncthreads();

    // ---- pass 2: recompute (bit-identical), append candidates <= thr ----
    for (int nn = 0; nn < 32; ++nn) {
        int nt = q * 32 + nn;
        f32x4 af = dot_tile(afr, cbh8, nt, lane);
        int   code = nt * 16 + lr;
        float cs1  = __fadd_rn(csl[code], 1.0f);
        #pragma unroll
        for (int j = 0; j < 4; ++j) {
            float s   = __fmaf_rn(-2.f, af[j], cs1);
            int   row = tile * 16 + lg * 4 + j;
            if (s <= thrsh[row]) {
                int pos = atomicAdd(&cnt, 1);
                if (pos < CAP) list[pos] = ((unsigned)row << 10) | (unsigned)code;
                else ovf = 1;
            }
        }
    }
    __syncthreads();

    // ---- exact rescore: x from LDS (bit-identical values), cb from L2 ----
    if (ovf || cnt > CAP) {
        for (int it = t; it < RPB * KCODES; it += 512) {   // safety net (never fires)
            int row = it >> 10, code = it & (KCODES - 1);
            float dot = exact_dot(&xl[row * XPITCH], cb + (size_t)code * DDIM);
            float s   = __fmaf_rn(-2.f, dot, __fadd_rn(csl[code], xsqr[r0 + row]));
            atomicMin(&keys[row], ((unsigned long long)__float_as_uint(s) << 32) | (unsigned)code);
        }
    } else {
        for (int i = t; i < cnt; i += 512) {
            unsigned e = list[i];
            int row = (int)(e >> 10), code = (int)(e & 0x3FFu);
            float dot = exact_dot(&xl[row * XPITCH], cb + (size_t)code * DDIM);
            float s   = __fmaf_rn(-2.f, dot, __fadd_rn(csl[code], xsqr[r0 + row]));   // r2-proven form
            atomicMin(&keys[row], ((unsigned long long)__float_as_uint(s) << 32) | (unsigned)code);
        }
    }
    __syncthreads();

    if (t < RPB) {
        int code = (int)(unsigned)(keys[t] & 0xffffffffu);
        fidx[t] = code;
        out[(size_t)2 * NROWS * DDIM + (r0 + t)] = (float)code;
    }
    __syncthreads();

    // gather winning codes: 64 rows x 64 float4, coalesced
    const float4* cb4  = (const float4*)cb;
    float4*       out0 = (float4*)out;
    float4*       out1 = out0 + (size_t)NROWS * (DDIM / 4);
    #pragma unroll
    for (int i = 0; i < 8; ++i) {
        int it  = i * 512 + t;
        int row = it >> 6, col = it & 63;
        float4 v = cb4[(size_t)fidx[row] * (DDIM / 4) + col];
        size_t o = (size_t)(r0 + row) * (DDIM / 4) + col;
        out0[o] = v;
        out1[o] = v;
    }
}

extern "C" void kernel_launch(void* const* d_in, const int* in_sizes, int n_in,
                              void* d_out, int out_size, void* d_ws, size_t ws_size,
                              hipStream_t stream) {
    const float* x   = (const float*)d_in[0];   // z_e_x   [32768,256]
    const float* cb  = (const float*)d_in[1];   // codebook [1024,256]
    float*       out = (float*)d_out;

    float* ws_csqr = (float*)d_ws;                // [1024]
    float* ws_xsqr = ws_csqr + KCODES;            // [32768]
    short* ws_cbh  = (short*)(ws_xsqr + NROWS);   // [1024*256] bf16 frags

    vq_cbfrag<<<128,        256, 0, stream>>>(cb, ws_cbh);
    vq_csqr  <<<256,        256, 0, stream>>>(cb, ws_csqr);
    vq_xsqr  <<<NROWS / 4,  256, 0, stream>>>(x, ws_xsqr);
    vq_main  <<<NROWS / RPB, 512, 0, stream>>>(x, cb, ws_cbh, ws_csqr, ws_xsqr, out);
}

// Round 9
// 94.053 us; speedup vs baseline: 3.2205x; 1.0626x over previous
//
#include <hip/hip_runtime.h>

// VQEmbedding: B=32,T=1024,D=256,K=1024. N=32768 rows.
// Exact score (proven r2-r6): s = fl32( fl32(csqr_k + xsqr_i) - 2*dot_ik ), argmin,
// first-index ties via packed u64 keys. bf16 MFMA approx (fragment layout verified
// r4-r6); two-pass margin filter (M=1.5e-3, proven r6); exact fp32 rescore (r2 chain).
// r7 change: B-fragments staged in double-buffered LDS and SHARED by the block's 4
// waves (r6 counters: 2GB private L2 B-reads = 60us was the bottleneck). Each wave
// covers all 1024 codes for its own 16 rows -> per-row thresholds live in registers.
// T14 staging: issue global loads early, ds_write after barrier, 1 barrier/chunk.
// (r7+r8 benches were infra failures — same wedged container, transport error before
//  push; kernel never ran. Resubmitted unchanged to preserve the A/B vs r6.)

#define NROWS  32768
#define DDIM   256
#define KCODES 1024
#define MARGIN 1.5e-3f
#define CAP    1024
#define RPB    64          // rows per block (4 waves x 16)
#define NCHUNK 16          // chunks per pass; chunk = 4 nt = 64 codes = 32KB frags

typedef __attribute__((ext_vector_type(8))) short short8;
typedef __attribute__((ext_vector_type(4))) float f32x4;

__device__ __forceinline__ unsigned short f2bf(float f) {   // RNE f32->bf16
    unsigned u = __float_as_uint(f);
    return (unsigned short)((u + 0x7FFFu + ((u >> 16) & 1u)) >> 16);
}

// exact fp32 dot — BIT-IDENTICAL chain to r2-r6 (proven). DO NOT reorder.
__device__ __forceinline__ float exact_dot(const float* __restrict__ xrow,
                                           const float* __restrict__ crow) {
    const float4* xp = (const float4*)xrow;
    const float4* cp = (const float4*)crow;
    float A = 0.f, B = 0.f;
    #pragma unroll 8
    for (int d4 = 0; d4 < 32; ++d4) {
        float4 xv = xp[d4], cv = cp[d4];
        A = __fmaf_rn(xv.x, cv.x, A);
        A = __fmaf_rn(xv.y, cv.y, A);
        A = __fmaf_rn(xv.z, cv.z, A);
        A = __fmaf_rn(xv.w, cv.w, A);
    }
    #pragma unroll 8
    for (int d4 = 32; d4 < 64; ++d4) {
        float4 xv = xp[d4], cv = cp[d4];
        B = __fmaf_rn(xv.x, cv.x, B);
        B = __fmaf_rn(xv.y, cv.y, B);
        B = __fmaf_rn(xv.z, cv.z, B);
        B = __fmaf_rn(xv.w, cv.w, B);
    }
    return __fadd_rn(A, B);
}

// --- csqr[k] (proven r2-r6, unchanged) ---
__global__ __launch_bounds__(256) void vq_csqr(const float* __restrict__ cb,
                                               float* __restrict__ csqr) {
    int gid  = blockIdx.x * 256 + threadIdx.x;
    int w    = gid >> 6;
    int lane = threadIdx.x & 63;
    if (w >= KCODES) return;
    float4 v = reinterpret_cast<const float4*>(cb)[w * (DDIM / 4) + lane];
    float s = v.x * v.x + v.y * v.y + v.z * v.z + v.w * v.w;
    #pragma unroll
    for (int off = 32; off > 0; off >>= 1) s += __shfl_down(s, off, 64);
    if (lane == 0) csqr[w] = s;
}

// --- xsqr[r] (proven r3-r6, unchanged) ---
__global__ __launch_bounds__(256) void vq_xsqr(const float* __restrict__ x,
                                               float* __restrict__ xsqr) {
    int w = threadIdx.x >> 6, lane = threadIdx.x & 63;
    int row = blockIdx.x * 4 + w;
    float4 v = reinterpret_cast<const float4*>(x + (size_t)row * DDIM)[lane];
    float s = v.x * v.x + v.y * v.y + v.z * v.z + v.w * v.w;
    #pragma unroll
    for (int off = 32; off > 0; off >>= 1) s += __shfl_down(s, off, 64);
    if (lane == 0) xsqr[row] = s;
}

// --- cb -> bf16 B-fragments (layout verified r4-r6): frag(nt,ks): lane l elem i =
//     cb[nt*16 + (l&15)][ks*32 + (l>>4)*8 + i]; linear id = (nt*8+ks)*64 + l ---
__global__ __launch_bounds__(256) void vq_cbfrag(const float* __restrict__ cb,
                                                 short* __restrict__ cbh) {
    int id   = blockIdx.x * 256 + threadIdx.x;
    int lane = id & 63;
    int ks   = (id >> 6) & 7;
    int nt   = id >> 9;
    int code = nt * 16 + (lane & 15);
    int d0   = ks * 32 + (lane >> 4) * 8;
    const float4* p = (const float4*)(cb + (size_t)code * DDIM + d0);
    float4 a = p[0], b = p[1];
    short8 v;
    v[0] = (short)f2bf(a.x); v[1] = (short)f2bf(a.y);
    v[2] = (short)f2bf(a.z); v[3] = (short)f2bf(a.w);
    v[4] = (short)f2bf(b.x); v[5] = (short)f2bf(b.y);
    v[6] = (short)f2bf(b.z); v[7] = (short)f2bf(b.w);
    *(short8*)(cbh + (size_t)id * 8) = v;
}

// --- main: 64 rows/block, 256 thr = 4 waves x 16 rows; B LDS-shared, double-buffered ---
__global__ __launch_bounds__(256, 2) void vq_main(const float* __restrict__ x,
                                                  const float* __restrict__ cb,
                                                  const short* __restrict__ cbh,
                                                  const float* __restrict__ csqr,
                                                  const float* __restrict__ xsqr,
                                                  float* __restrict__ out) {
    __shared__ short              bstage[2][4 * 8 * 64 * 8];  // 2 x 32KB B chunks
    __shared__ float              csl[KCODES];                // 4KB
    __shared__ unsigned long long keys[RPB];
    __shared__ unsigned           list[CAP];
    __shared__ int                fidx[RPB];
    __shared__ int                cnt, ovf;

    const int t    = threadIdx.x;
    const int lane = t & 63;
    const int w    = t >> 6;         // 0..3 (wave = 16-row tile)
    const int r0   = blockIdx.x * RPB;
    const int lr   = lane & 15;
    const int lg   = lane >> 4;

    ((float4*)csl)[t] = ((const float4*)csqr)[t];
    if (t < RPB) keys[t] = ~0ULL;
    if (t == 0) { cnt = 0; ovf = 0; }

    // A-fragments direct from global (x is read once; L3-resident). Mapping as r4-r6.
    short8 afr[8];
    {
        const float* xr = x + (size_t)(r0 + w * 16 + lr) * DDIM;
        #pragma unroll
        for (int ks = 0; ks < 8; ++ks) {
            float4 a = *(const float4*)&xr[ks * 32 + lg * 8];
            float4 b = *(const float4*)&xr[ks * 32 + lg * 8 + 4];
            short8 v;
            v[0] = (short)f2bf(a.x); v[1] = (short)f2bf(a.y);
            v[2] = (short)f2bf(a.z); v[3] = (short)f2bf(a.w);
            v[4] = (short)f2bf(b.x); v[5] = (short)f2bf(b.y);
            v[6] = (short)f2bf(b.z); v[7] = (short)f2bf(b.w);
            afr[ks] = v;
        }
    }

    const short8* cbh8 = (const short8*)cbh;   // fragment-linear, 16B units

    // T14 pipeline state: pf holds chunk (c+1) while computing chunk c.
    short8 pf[8];
    #pragma unroll
    for (int i = 0; i < 8; ++i) pf[i] = cbh8[(size_t)0 * 2048 + i * 256 + t];   // chunk 0
    {   // write chunk 0 -> buf0, start chunk 1 loads
        short8* dst = (short8*)bstage[0];
        #pragma unroll
        for (int i = 0; i < 8; ++i) dst[i * 256 + t] = pf[i];
        #pragma unroll
        for (int i = 0; i < 8; ++i) pf[i] = cbh8[(size_t)1 * 2048 + i * 256 + t];   // chunk 1
    }
    __syncthreads();

    unsigned runp[4];
    #pragma unroll
    for (int j = 0; j < 4; ++j) runp[j] = ~0u;
    float thr[4];

    for (int c = 0; c < 2 * NCHUNK; ++c) {
        const int q = c & (NCHUNK - 1);          // physical chunk 0..15
        // 1) write prefetched chunk c+1 into the buffer read LAST iter (safe post-barrier)
        if (c + 1 < 2 * NCHUNK) {
            short8* dst = (short8*)bstage[(c + 1) & 1];
            #pragma unroll
            for (int i = 0; i < 8; ++i) dst[i * 256 + t] = pf[i];
        }
        // 2) issue global loads for chunk c+2 (latency hides under compute)
        if (c + 2 < 2 * NCHUNK) {
            const size_t cb2 = (size_t)((c + 2) & (NCHUNK - 1)) * 2048;
            #pragma unroll
            for (int i = 0; i < 8; ++i) pf[i] = cbh8[cb2 + i * 256 + t];
        }
        // 3) compute chunk c from buf[c&1]
        const short* bs = bstage[c & 1];
        #pragma unroll
        for (int m = 0; m < 4; ++m) {
            const int nt = q * 4 + m;
            short8 bv[8];
            #pragma unroll
            for (int ks = 0; ks < 8; ++ks)
                bv[ks] = *(const short8*)&bs[((m * 8 + ks) * 64 + lane) * 8];
            f32x4 af = (f32x4){0.f, 0.f, 0.f, 0.f};
            #pragma unroll
            for (int ks = 0; ks < 8; ++ks)
                af = __builtin_amdgcn_mfma_f32_16x16x32_bf16(afr[ks], bv[ks], af, 0, 0, 0);

            const int code = nt * 16 + lr;
            float cs1 = __fadd_rn(csl[code], 1.0f);   // +1: score>0 -> bit order = float order
            if (c < NCHUNK) {
                // pass 1: packed coarse min (r6-proven form)
                #pragma unroll
                for (int j = 0; j < 4; ++j) {
                    float s = __fmaf_rn(-2.f, af[j], cs1);
                    unsigned kp = (__float_as_uint(s) & 0xFFFFFC00u) | (unsigned)code;
                    runp[j] = runp[j] < kp ? runp[j] : kp;
                }
            } else {
                // pass 2: bit-identical recompute, append candidates
                #pragma unroll
                for (int j = 0; j < 4; ++j) {
                    float s = __fmaf_rn(-2.f, af[j], cs1);
                    if (s <= thr[j]) {
                        int row = w * 16 + lg * 4 + j;
                        int pos = atomicAdd(&cnt, 1);
                        if (pos < CAP) list[pos] = ((unsigned)row << 10) | (unsigned)code;
                        else ovf = 1;
                    }
                }
            }
        }
        // pass-1 -> pass-2 boundary: butterfly over the 16 lr lanes, thresholds in regs
        if (c == NCHUNK - 1) {
            #pragma unroll
            for (int j = 0; j < 4; ++j) {
                unsigned v = runp[j];
                #pragma unroll
                for (int mm = 1; mm < 16; mm <<= 1) {
                    unsigned o = __shfl_xor(v, mm, 64);
                    v = o < v ? o : v;
                }
                thr[j] = __uint_as_float(v & 0xFFFFFC00u) + MARGIN;
            }
        }
        __syncthreads();   // chunk c+1 visible; readers of buf[c&1] done
    }

    // ---- exact rescore (r2-proven chain + grid formula), u64 first-index argmin ----
    if (ovf || cnt > CAP) {
        for (int it = t; it < RPB * KCODES; it += 256) {   // safety net (never fires)
            int row = it >> 10, code = it & (KCODES - 1);
            float dot = exact_dot(x + (size_t)(r0 + row) * DDIM, cb + (size_t)code * DDIM);
            float s   = __fmaf_rn(-2.f, dot, __fadd_rn(csl[code], xsqr[r0 + row]));
            atomicMin(&keys[row], ((unsigned long long)__float_as_uint(s) << 32) | (unsigned)code);
        }
    } else {
        for (int i = t; i < cnt; i += 256) {
            unsigned e = list[i];
            int row = (int)(e >> 10), code = (int)(e & 0x3FFu);
            float dot = exact_dot(x + (size_t)(r0 + row) * DDIM, cb + (size_t)code * DDIM);
            float s   = __fmaf_rn(-2.f, dot, __fadd_rn(csl[code], xsqr[r0 + row]));
            atomicMin(&keys[row], ((unsigned long long)__float_as_uint(s) << 32) | (unsigned)code);
        }
    }
    __syncthreads();

    if (t < RPB) {
        int code = (int)(unsigned)(keys[t] & 0xffffffffu);
        fidx[t] = code;
        out[(size_t)2 * NROWS * DDIM + (r0 + t)] = (float)code;
    }
    __syncthreads();

    // gather winning codes: 64 rows x 64 float4, coalesced
    const float4* cb4  = (const float4*)cb;
    float4*       out0 = (float4*)out;
    float4*       out1 = out0 + (size_t)NROWS * (DDIM / 4);
    #pragma unroll
    for (int i = 0; i < 16; ++i) {
        int it  = i * 256 + t;
        int row = it >> 6, col = it & 63;
        float4 v = cb4[(size_t)fidx[row] * (DDIM / 4) + col];
        size_t o = (size_t)(r0 + row) * (DDIM / 4) + col;
        out0[o] = v;
        out1[o] = v;
    }
}

extern "C" void kernel_launch(void* const* d_in, const int* in_sizes, int n_in,
                              void* d_out, int out_size, void* d_ws, size_t ws_size,
                              hipStream_t stream) {
    const float* x   = (const float*)d_in[0];   // z_e_x   [32768,256]
    const float* cb  = (const float*)d_in[1];   // codebook [1024,256]
    float*       out = (float*)d_out;

    float* ws_csqr = (float*)d_ws;                // [1024]
    float* ws_xsqr = ws_csqr + KCODES;            // [32768]
    short* ws_cbh  = (short*)(ws_xsqr + NROWS);   // [1024*256] bf16 frags

    vq_cbfrag<<<128,        256, 0, stream>>>(cb, ws_cbh);
    vq_csqr  <<<256,        256, 0, stream>>>(cb, ws_csqr);
    vq_xsqr  <<<NROWS / 4,  256, 0, stream>>>(x, ws_xsqr);
    vq_main  <<<NROWS / RPB, 256, 0, stream>>>(x, cb, ws_cbh, ws_csqr, ws_xsqr, out);
}